// Round 6
// baseline (201.454 us; speedup 1.0000x reference)
//
#include <hip/hip_runtime.h>
#include <hip/hip_bf16.h>

// DIAGNOSTIC ROUND: R4 structure, whole workload executed TWICE per launch
// (rep loop, idempotent stores, memory-clobber between reps so pass 2 is not
// CSE'd). Purpose: push pkl_kernel above the harness's 77 us poison fills so
// rocprof top-5 shows its counters again (lost since R2). Pass 2 is fully
// cache-warm over identical addresses -> dur vs 2x single-pass also measures
// the cold-miss latency share.
#define SS 4096
#define CC 64
#define PST 72            // LDS row stride in bf16 (144 B = 9 x 16 B)
#define NROWS 129

typedef __attribute__((ext_vector_type(8))) short short8;
typedef __attribute__((ext_vector_type(4))) float floatx4;

static __device__ __forceinline__ unsigned short f2bf(float f) {
    __hip_bfloat16 h = __float2bfloat16(f);
    return *reinterpret_cast<unsigned short*>(&h);
}
static __device__ __forceinline__ float bf2f(unsigned short u) {
    __hip_bfloat16 h; *reinterpret_cast<unsigned short*>(&h) = u;
    return __bfloat162float(h);
}
static __device__ __forceinline__ float f4c(const float4& v, int k) {
    switch (k & 3) { case 0: return v.x; case 1: return v.y; case 2: return v.z; default: return v.w; }
}

// DPP cross-lane reductions (VALU pipe, no LDS traffic)
#define DPP_QX1 0xB1   // quad_perm xor1
#define DPP_QX2 0x4E   // quad_perm xor2
#define DPP_HM  0x141  // row_half_mirror (xor7 in 8)
#define DPP_RM  0x140  // row_mirror (xor15 in 16)
template<int CTRL>
static __device__ __forceinline__ float dpp_fadd(float v) {
    int p = __builtin_amdgcn_update_dpp(0, __float_as_int(v), CTRL, 0xf, 0xf, true);
    return v + __int_as_float(p);
}
template<int CTRL>
static __device__ __forceinline__ float dpp_fmax(float v) {
    int p = __builtin_amdgcn_update_dpp(0, __float_as_int(v), CTRL, 0xf, 0xf, true);
    return fmaxf(v, __int_as_float(p));
}

__global__ __launch_bounds__(256, 4) void pkl_kernel(
        const float* __restrict__ logits,
        const float* __restrict__ M,
        float* __restrict__ out) {
    __shared__ __hip_bfloat16 mt_lds[CC * PST];      // M rows, sigma cols
    __shared__ __hip_bfloat16 pt_lds[NROWS * PST];   // block P tile, sigma cols

    const int tid  = threadIdx.x;
    const int lane = tid & 63;
    const int w    = tid >> 6;
    const int quad = lane >> 4;   // 0..3
    const int nlo  = lane & 15;   // 0..15
    const int rq   = lane >> 2;   // softmax: row-within-wave 0..15
    const int q    = lane & 3;    // softmax: quarter of row

    const int b  = blockIdx.x >> 5;            // 32 blocks per batch row
    const int s0 = (blockIdx.x & 31) * 128;    // block's first position
    const float* lg = logits + (size_t)b * SS * CC;
    const float LOG2E = 1.4426950408889634f, LN2 = 0.6931471805599453f;

    // ---- one-time: stage M into LDS with sigma columns ----
    #pragma unroll
    for (int j = 0; j < 16; ++j) {
        int idx = j * 256 + tid, c = idx >> 6, d = idx & 63;
        mt_lds[c * PST + 4 * (d & 15) + (d >> 4)] = __float2bfloat16(M[idx]);
    }

    for (int rep = 0; rep < 2; ++rep) {
        __syncthreads();                        // protect pt_lds WAR across reps
        asm volatile("" ::: "memory");          // forbid cross-rep CSE of loads

        // ---- phase 1a: all global loads up front (4 lanes/row, 16 floats/lane) ----
        float4 xa[2][4];
        #pragma unroll
        for (int i = 0; i < 2; ++i) {
            const int lr = i * 64 + w * 16 + rq;             // 0..127
            const float* rp = lg + (size_t)(s0 + lr) * CC;
            #pragma unroll
            for (int j = 0; j < 4; ++j)
                xa[i][j] = *reinterpret_cast<const float4*>(rp + (j * 4 + q) * 4);
        }

        // ---- phase 1b: softmax (16 in-lane + 2 DPP steps over the 4-lane quad) ----
        #pragma unroll
        for (int i = 0; i < 2; ++i) {
            const int lr = i * 64 + w * 16 + rq;
            float mx = f4c(xa[i][0], 0);
            #pragma unroll
            for (int j = 0; j < 4; ++j)
                #pragma unroll
                for (int k = 0; k < 4; ++k)
                    mx = fmaxf(mx, f4c(xa[i][j], k));
            mx = dpp_fmax<DPP_QX1>(mx); mx = dpp_fmax<DPP_QX2>(mx);
            float sm = 0.f;
            #pragma unroll
            for (int j = 0; j < 4; ++j)
                #pragma unroll
                for (int k = 0; k < 4; ++k)
                    sm += exp2f((f4c(xa[i][j], k) - mx) * LOG2E);
            sm = dpp_fadd<DPP_QX1>(sm); sm = dpp_fadd<DPP_QX2>(sm);
            const float lse = mx + log2f(sm) * LN2;
            short8 h0, h1;
            #pragma unroll
            for (int o = 0; o < 8; ++o) {                    // o = 4k+j, c' = 16q+o
                h0[o] = (short)f2bf(f4c(xa[i][o & 3], o >> 2) - lse);
                h1[o] = (short)f2bf(f4c(xa[i][(o + 8) & 3], (o + 8) >> 2) - lse);
            }
            short* pp = reinterpret_cast<short*>(pt_lds) + lr * PST + 16 * q;
            *reinterpret_cast<short8*>(pp) = h0;
            *reinterpret_cast<short8*>(pp + 8) = h1;
        }

        // ---- overlap row 128: lanes 0..3 of wave 0 ----
        if (tid < 4) {
            const int grow = min(s0 + 128, SS - 1);
            const float* rp = lg + (size_t)grow * CC;
            float4 y[4];
            #pragma unroll
            for (int j = 0; j < 4; ++j)
                y[j] = *reinterpret_cast<const float4*>(rp + (j * 4 + tid) * 4);
            float mx = f4c(y[0], 0);
            #pragma unroll
            for (int j = 0; j < 4; ++j)
                #pragma unroll
                for (int k = 0; k < 4; ++k)
                    mx = fmaxf(mx, f4c(y[j], k));
            mx = dpp_fmax<DPP_QX1>(mx); mx = dpp_fmax<DPP_QX2>(mx);
            float sm = 0.f;
            #pragma unroll
            for (int j = 0; j < 4; ++j)
                #pragma unroll
                for (int k = 0; k < 4; ++k)
                    sm += exp2f((f4c(y[j], k) - mx) * LOG2E);
            sm = dpp_fadd<DPP_QX1>(sm); sm = dpp_fadd<DPP_QX2>(sm);
            const float lse = mx + log2f(sm) * LN2;
            short8 h0, h1;
            #pragma unroll
            for (int o = 0; o < 8; ++o) {
                h0[o] = (short)f2bf(f4c(y[o & 3], o >> 2) - lse);
                h1[o] = (short)f2bf(f4c(y[(o + 8) & 3], (o + 8) >> 2) - lse);
            }
            short* pp = reinterpret_cast<short*>(pt_lds) + 128 * PST + 16 * tid;
            *reinterpret_cast<short8*>(pp) = h0;
            *reinterpret_cast<short8*>(pp + 8) = h1;
        }
        __syncthreads();

        // ---- phase 2: MFMA 16x16x32 (sigma-k) ----
        floatx4 acc[2][4];
        #pragma unroll
        for (int mt = 0; mt < 2; ++mt)
            #pragma unroll
            for (int nt = 0; nt < 4; ++nt)
                acc[mt][nt] = (floatx4){0.f, 0.f, 0.f, 0.f};
        #pragma unroll
        for (int kt = 0; kt < 2; ++kt) {
            const int koff = kt * 32 + quad * 8;
            short8 bfrag[4];
            #pragma unroll
            for (int nt = 0; nt < 4; ++nt)
                bfrag[nt] = *reinterpret_cast<const short8*>(
                    reinterpret_cast<const short*>(mt_lds) + (nt * 16 + nlo) * PST + koff);
            #pragma unroll
            for (int mt = 0; mt < 2; ++mt) {
                short8 afrag = *reinterpret_cast<const short8*>(
                    reinterpret_cast<const short*>(pt_lds) + (w * 32 + 1 + mt * 16 + nlo) * PST + koff);
                #pragma unroll
                for (int nt = 0; nt < 4; ++nt)
                    acc[mt][nt] = __builtin_amdgcn_mfma_f32_16x16x32_bf16(
                        afrag, bfrag[nt], acc[mt][nt], 0, 0, 0);
            }
        }

        // ---- phase 3: r[t] = dot(p_t, V[t+1]) from accumulators ----
        const size_t outbase = (size_t)b * (SS - 1);
        #pragma unroll
        for (int mt = 0; mt < 2; ++mt)
            #pragma unroll
            for (int r = 0; r < 4; ++r) {
                const int lrow = w * 32 + mt * 16 + quad * 4 + r;
                ushort4 pd = *reinterpret_cast<const ushort4*>(
                    reinterpret_cast<const unsigned short*>(pt_lds) + lrow * PST + 4 * nlo);
                float s = bf2f(pd.x) * acc[mt][0][r] + bf2f(pd.y) * acc[mt][1][r]
                        + bf2f(pd.z) * acc[mt][2][r] + bf2f(pd.w) * acc[mt][3][r];
                s = dpp_fadd<DPP_QX1>(s); s = dpp_fadd<DPP_QX2>(s);
                s = dpp_fadd<DPP_HM>(s);  s = dpp_fadd<DPP_RM>(s);
                if (nlo == 0) {
                    const int t = s0 + lrow;
                    if (t <= SS - 2) out[outbase + t] = s;
                }
            }
    }
}

extern "C" void kernel_launch(void* const* d_in, const int* in_sizes, int n_in,
                              void* d_out, int out_size, void* d_ws, size_t ws_size,
                              hipStream_t stream) {
    const float* logits = (const float*)d_in[0];   // [128, 4096, 64] fp32
    const float* M      = (const float*)d_in[1];   // [64, 64] fp32
    float* out          = (float*)d_out;           // [128, 4095] fp32

    dim3 grid(128 * 32), block(256);
    hipLaunchKernelGGL(pkl_kernel, grid, block, 0, stream, logits, M, out);
}

// Round 7
// 188.172 us; speedup vs baseline: 1.0706x; 1.0706x over previous
//
#include <hip/hip_runtime.h>
#include <hip/hip_bf16.h>

// FINAL (revert of R6 diagnostic to the best-measured kernel, 188.8 us total).
// Problem: B=128, S=4096, C=64.  r[b,t] = p_t . (M p_{t+1}),  p = log_softmax(logits)
// sigma-permuted class storage in LDS: c' = 4*(c&15) + (c>>4), applied to BOTH P and M
// (MFMA is invariant to a shared k-permutation); phase 3 reads each lane's 4 classes
// {16nt+nlo} as one contiguous ds_read_b64 at c' = 4*nlo.
// Measured structure (R6 rep-diagnostic): warm full pass = 12.7 us -> compute fits in
// ~13 us; cold pass ~19 us vs ~17 us memory floor (134 MB fp32 logits read once,
// L3 retains ~half). Remaining ~170 us of dur_us is harness poison/restore traffic.
#define SS 4096
#define CC 64
#define PST 72            // LDS row stride in bf16 (144 B = 9 x 16 B)
#define NROWS 129

typedef __attribute__((ext_vector_type(8))) short short8;
typedef __attribute__((ext_vector_type(4))) float floatx4;

static __device__ __forceinline__ unsigned short f2bf(float f) {
    __hip_bfloat16 h = __float2bfloat16(f);
    return *reinterpret_cast<unsigned short*>(&h);
}
static __device__ __forceinline__ float bf2f(unsigned short u) {
    __hip_bfloat16 h; *reinterpret_cast<unsigned short*>(&h) = u;
    return __bfloat162float(h);
}
static __device__ __forceinline__ float f4c(const float4& v, int k) {
    switch (k & 3) { case 0: return v.x; case 1: return v.y; case 2: return v.z; default: return v.w; }
}

// DPP cross-lane reductions (VALU pipe, no LDS traffic)
#define DPP_QX1 0xB1   // quad_perm xor1
#define DPP_QX2 0x4E   // quad_perm xor2
#define DPP_HM  0x141  // row_half_mirror (xor7 in 8)
#define DPP_RM  0x140  // row_mirror (xor15 in 16)
template<int CTRL>
static __device__ __forceinline__ float dpp_fadd(float v) {
    int p = __builtin_amdgcn_update_dpp(0, __float_as_int(v), CTRL, 0xf, 0xf, true);
    return v + __int_as_float(p);
}
template<int CTRL>
static __device__ __forceinline__ float dpp_fmax(float v) {
    int p = __builtin_amdgcn_update_dpp(0, __float_as_int(v), CTRL, 0xf, 0xf, true);
    return fmaxf(v, __int_as_float(p));
}

__global__ __launch_bounds__(256, 4) void pkl_kernel(
        const float* __restrict__ logits,
        const float* __restrict__ M,
        float* __restrict__ out) {
    __shared__ __hip_bfloat16 mt_lds[CC * PST];      // M rows, sigma cols
    __shared__ __hip_bfloat16 pt_lds[NROWS * PST];   // block P tile, sigma cols

    const int tid  = threadIdx.x;
    const int lane = tid & 63;
    const int w    = tid >> 6;
    const int quad = lane >> 4;   // 0..3
    const int nlo  = lane & 15;   // 0..15
    const int rq   = lane >> 2;   // softmax: row-within-wave 0..15
    const int q    = lane & 3;    // softmax: quarter of row

    const int b  = blockIdx.x >> 5;            // 32 blocks per batch row
    const int s0 = (blockIdx.x & 31) * 128;    // block's first position
    const float* lg = logits + (size_t)b * SS * CC;
    const float LOG2E = 1.4426950408889634f, LN2 = 0.6931471805599453f;

    // ---- phase 1a: all global loads up front (4 lanes/row, 16 floats/lane, coalesced) ----
    float4 xa[2][4];
    #pragma unroll
    for (int i = 0; i < 2; ++i) {
        const int lr = i * 64 + w * 16 + rq;             // 0..127
        const float* rp = lg + (size_t)(s0 + lr) * CC;
        #pragma unroll
        for (int j = 0; j < 4; ++j)
            xa[i][j] = *reinterpret_cast<const float4*>(rp + (j * 4 + q) * 4);
    }

    // ---- stage M into LDS with sigma columns (M is L2-resident) ----
    #pragma unroll
    for (int j = 0; j < 16; ++j) {
        int idx = j * 256 + tid, c = idx >> 6, d = idx & 63;
        mt_lds[c * PST + 4 * (d & 15) + (d >> 4)] = __float2bfloat16(M[idx]);
    }

    // ---- phase 1b: softmax (16 in-lane values + 2 DPP steps over the 4-lane quad) ----
    #pragma unroll
    for (int i = 0; i < 2; ++i) {
        const int lr = i * 64 + w * 16 + rq;
        float mx = f4c(xa[i][0], 0);
        #pragma unroll
        for (int j = 0; j < 4; ++j)
            #pragma unroll
            for (int k = 0; k < 4; ++k)
                mx = fmaxf(mx, f4c(xa[i][j], k));
        mx = dpp_fmax<DPP_QX1>(mx); mx = dpp_fmax<DPP_QX2>(mx);
        float sm = 0.f;
        #pragma unroll
        for (int j = 0; j < 4; ++j)
            #pragma unroll
            for (int k = 0; k < 4; ++k)
                sm += exp2f((f4c(xa[i][j], k) - mx) * LOG2E);
        sm = dpp_fadd<DPP_QX1>(sm); sm = dpp_fadd<DPP_QX2>(sm);
        const float lse = mx + log2f(sm) * LN2;
        short8 h0, h1;
        #pragma unroll
        for (int o = 0; o < 8; ++o) {                    // o = 4k+j, c' = 16q+o
            h0[o] = (short)f2bf(f4c(xa[i][o & 3], o >> 2) - lse);
            h1[o] = (short)f2bf(f4c(xa[i][(o + 8) & 3], (o + 8) >> 2) - lse);
        }
        short* pp = reinterpret_cast<short*>(pt_lds) + lr * PST + 16 * q;
        *reinterpret_cast<short8*>(pp) = h0;
        *reinterpret_cast<short8*>(pp + 8) = h1;
    }

    // ---- overlap row 128 (= next block's row 0): lanes 0..3 of wave 0 ----
    if (tid < 4) {
        const int grow = min(s0 + 128, SS - 1);
        const float* rp = lg + (size_t)grow * CC;
        float4 y[4];
        #pragma unroll
        for (int j = 0; j < 4; ++j)
            y[j] = *reinterpret_cast<const float4*>(rp + (j * 4 + tid) * 4);
        float mx = f4c(y[0], 0);
        #pragma unroll
        for (int j = 0; j < 4; ++j)
            #pragma unroll
            for (int k = 0; k < 4; ++k)
                mx = fmaxf(mx, f4c(y[j], k));
        mx = dpp_fmax<DPP_QX1>(mx); mx = dpp_fmax<DPP_QX2>(mx);
        float sm = 0.f;
        #pragma unroll
        for (int j = 0; j < 4; ++j)
            #pragma unroll
            for (int k = 0; k < 4; ++k)
                sm += exp2f((f4c(y[j], k) - mx) * LOG2E);
        sm = dpp_fadd<DPP_QX1>(sm); sm = dpp_fadd<DPP_QX2>(sm);
        const float lse = mx + log2f(sm) * LN2;
        short8 h0, h1;
        #pragma unroll
        for (int o = 0; o < 8; ++o) {
            h0[o] = (short)f2bf(f4c(y[o & 3], o >> 2) - lse);
            h1[o] = (short)f2bf(f4c(y[(o + 8) & 3], (o + 8) >> 2) - lse);
        }
        short* pp = reinterpret_cast<short*>(pt_lds) + 128 * PST + 16 * tid;
        *reinterpret_cast<short8*>(pp) = h0;
        *reinterpret_cast<short8*>(pp + 8) = h1;
    }
    __syncthreads();

    // ---- phase 2: V[i][c] = sum_d P[w*32+1+i][d] * M[c][d], MFMA 16x16x32 (sigma-k) ----
    floatx4 acc[2][4];
    #pragma unroll
    for (int mt = 0; mt < 2; ++mt)
        #pragma unroll
        for (int nt = 0; nt < 4; ++nt)
            acc[mt][nt] = (floatx4){0.f, 0.f, 0.f, 0.f};
    #pragma unroll
    for (int kt = 0; kt < 2; ++kt) {
        const int koff = kt * 32 + quad * 8;
        short8 bfrag[4];
        #pragma unroll
        for (int nt = 0; nt < 4; ++nt)
            bfrag[nt] = *reinterpret_cast<const short8*>(
                reinterpret_cast<const short*>(mt_lds) + (nt * 16 + nlo) * PST + koff);
        #pragma unroll
        for (int mt = 0; mt < 2; ++mt) {
            short8 afrag = *reinterpret_cast<const short8*>(
                reinterpret_cast<const short*>(pt_lds) + (w * 32 + 1 + mt * 16 + nlo) * PST + koff);
            #pragma unroll
            for (int nt = 0; nt < 4; ++nt)
                acc[mt][nt] = __builtin_amdgcn_mfma_f32_16x16x32_bf16(
                    afrag, bfrag[nt], acc[mt][nt], 0, 0, 0);
        }
    }

    // ---- phase 3: r[t] = dot(p_t, V[t+1]) from accumulators.
    //      acc[mt][nt][r] = V[w*32+1+mt*16+quad*4+r][16nt+nlo]; lane's 4 p-classes are
    //      contiguous at sigma c' = 4*nlo -> one ds_read_b64 per row. ----
    const size_t outbase = (size_t)b * (SS - 1);
    #pragma unroll
    for (int mt = 0; mt < 2; ++mt)
        #pragma unroll
        for (int r = 0; r < 4; ++r) {
            const int lrow = w * 32 + mt * 16 + quad * 4 + r;
            ushort4 pd = *reinterpret_cast<const ushort4*>(
                reinterpret_cast<const unsigned short*>(pt_lds) + lrow * PST + 4 * nlo);
            float s = bf2f(pd.x) * acc[mt][0][r] + bf2f(pd.y) * acc[mt][1][r]
                    + bf2f(pd.z) * acc[mt][2][r] + bf2f(pd.w) * acc[mt][3][r];
            s = dpp_fadd<DPP_QX1>(s); s = dpp_fadd<DPP_QX2>(s);
            s = dpp_fadd<DPP_HM>(s);  s = dpp_fadd<DPP_RM>(s);
            if (nlo == 0) {
                const int t = s0 + lrow;
                if (t <= SS - 2) out[outbase + t] = s;
            }
        }
}

extern "C" void kernel_launch(void* const* d_in, const int* in_sizes, int n_in,
                              void* d_out, int out_size, void* d_ws, size_t ws_size,
                              hipStream_t stream) {
    const float* logits = (const float*)d_in[0];   // [128, 4096, 64] fp32
    const float* M      = (const float*)d_in[1];   // [64, 64] fp32
    float* out          = (float*)d_out;           // [128, 4095] fp32

    dim3 grid(128 * 32), block(256);               // 128 outputs per block
    hipLaunchKernelGGL(pkl_kernel, grid, block, 0, stream, logits, M, out);
}